// Round 5
// baseline (944.397 us; speedup 1.0000x reference)
//
#include <hip/hip_runtime.h>
#include <hip/hip_bf16.h>
#include <stdint.h>

#define M_TOK 8192
#define KDIM  4096
#define NDIM  11008
#define NBLK  256      // KDIM / 16
#define K2    8192     // KDIM * 2 bytes (row stride of xt/wd)

typedef __bf16 bf16x8 __attribute__((ext_vector_type(8)));
typedef float  f32x4  __attribute__((ext_vector_type(4)));
typedef float  f32x16 __attribute__((ext_vector_type(16)));
typedef unsigned short ushort8 __attribute__((ext_vector_type(8)));

__device__ __forceinline__ unsigned short f2b(float f) {
    union { float f; unsigned int i; } v; v.f = f;
    unsigned int u = v.i;
    unsigned int r = (u + 0x7fffu + ((u >> 16) & 1u)) >> 16;
    return (unsigned short)r;
}

__device__ __forceinline__ void gl_lds16(const void* g, void* l) {
    __builtin_amdgcn_global_load_lds(
        (const __attribute__((address_space(1))) unsigned int*)g,
        (__attribute__((address_space(3))) unsigned int*)l, 16, 0, 0);
}

// ---------------------------------------------------------------------------
// Kernel 1: xt[m, b*16+j] = sum_i x[m, perm[b*16+i]] * R[b, i, j]  (f32 -> bf16)
// ---------------------------------------------------------------------------
__global__ __launch_bounds__(256) void rotate_kernel(
    const float* __restrict__ x, const float* __restrict__ R,
    const int* __restrict__ perm, unsigned short* __restrict__ xt)
{
    __shared__ float Rs[16][17];
    __shared__ int   ps[16];
    const int b = blockIdx.x;
    const int t = threadIdx.x;
    Rs[t >> 4][t & 15] = R[b * 256 + t];
    if (t < 16) ps[t] = perm[b * 16 + t];
    __syncthreads();

    const int m = blockIdx.y * 256 + t;
    const float* xrow = x + (size_t)m * KDIM;
    float xv[16];
#pragma unroll
    for (int i = 0; i < 16; ++i) xv[i] = xrow[ps[i]];

    unsigned short o[16] __attribute__((aligned(16)));
#pragma unroll
    for (int j = 0; j < 16; ++j) {
        float acc = 0.f;
#pragma unroll
        for (int i = 0; i < 16; ++i) acc += xv[i] * Rs[i][j];
        o[j] = f2b(acc);
    }
    unsigned short* dst = xt + (size_t)m * KDIM + b * 16;
    *(ushort8*)dst       = *(ushort8*)o;
    *(ushort8*)(dst + 8) = *(ushort8*)(o + 8);
}

// ---------------------------------------------------------------------------
// Kernel 2: Wd[n,k] = (float(q[n,k]) - zeros[n]) * scales[n] -> bf16
// ---------------------------------------------------------------------------
__global__ __launch_bounds__(256) void dequant_kernel(
    const int* __restrict__ q, const float* __restrict__ scales,
    const float* __restrict__ zeros, unsigned short* __restrict__ w)
{
    const int idx8 = blockIdx.x * 256 + threadIdx.x;
    const size_t base = (size_t)idx8 * 8;
    const int n = (int)(base >> 12);
    const float s = scales[n];
    const float z = zeros[n];
    const int4* qp = (const int4*)(q + base);
    const int4 q0 = qp[0], q1 = qp[1];
    unsigned short o[8] __attribute__((aligned(16)));
    o[0] = f2b(((float)q0.x - z) * s);
    o[1] = f2b(((float)q0.y - z) * s);
    o[2] = f2b(((float)q0.z - z) * s);
    o[3] = f2b(((float)q0.w - z) * s);
    o[4] = f2b(((float)q1.x - z) * s);
    o[5] = f2b(((float)q1.y - z) * s);
    o[6] = f2b(((float)q1.z - z) * s);
    o[7] = f2b(((float)q1.w - z) * s);
    *(ushort8*)(w + base) = *(ushort8*)o;
}

// ---------------------------------------------------------------------------
// Kernel 3: 256x256 8-phase GEMM, NOW with v_mfma_f32_32x32x16_bf16.
// A: xt (M x K bf16), B: wd (N x K bf16), C: f32.
// 512 threads = 8 waves (2M x 4N); BK=64; LDS 128 KiB (2 buffers).
// Per wave: 128x64 output = 4x2 frags of 32x32 (f32x16 each).
// Fragment maps: A/B  row|col = lane&31, k = (lane>>5)*8 + i (one b128 read);
//                C/D  col = lane&31, row = (reg&3)+8*(reg>>2)+4*(lane>>5).
// T2 swizzle identical to round 4 (0 conflicts measured): byte ^= (row&7)<<4,
// staging pre-swizzles the GLOBAL source, LDS dest linear. vmcnt(4) counted.
// ---------------------------------------------------------------------------
#define ABASE(bb) ((bb)*65536)
#define BBASE(bb) ((bb)*65536 + 32768)

#define BAR() do { asm volatile("" ::: "memory"); __builtin_amdgcn_s_barrier(); \
                   asm volatile("" ::: "memory"); } while (0)
#define WAITV(n) asm volatile("s_waitcnt vmcnt(" #n ")" ::: "memory")
#define PRIO1 __builtin_amdgcn_s_setprio(1)
#define PRIO0 __builtin_amdgcn_s_setprio(0)

#define STAGE_A(bb, kB) do { \
    gl_lds16(aStageBase + (size_t)(  0)*K2 + (kB), lds + ABASE(bb) +     0 + wOff); \
    gl_lds16(aStageBase + (size_t)( 64)*K2 + (kB), lds + ABASE(bb) +  8192 + wOff); \
    gl_lds16(aStageBase + (size_t)(128)*K2 + (kB), lds + ABASE(bb) + 16384 + wOff); \
    gl_lds16(aStageBase + (size_t)(192)*K2 + (kB), lds + ABASE(bb) + 24576 + wOff); \
} while (0)
#define STAGE_B0(bb, kB) do { \
    gl_lds16(bStageBase + (size_t)(  0)*K2 + (kB), lds + BBASE(bb) +     0 + wOff); \
    gl_lds16(bStageBase + (size_t)( 64)*K2 + (kB), lds + BBASE(bb) +  8192 + wOff); \
} while (0)
#define STAGE_B1(bb, kB) do { \
    gl_lds16(bStageBase + (size_t)(128)*K2 + (kB), lds + BBASE(bb) + 16384 + wOff); \
    gl_lds16(bStageBase + (size_t)(192)*K2 + (kB), lds + BBASE(bb) + 24576 + wOff); \
} while (0)

// A frags for half mh (2 m-quads x 4 k-steps = 8 x ds_read_b128)
#define PH_READ_A(bb, mh) do { \
    _Pragma("unroll") \
    for (int mq = 0; mq < 2; ++mq) \
    _Pragma("unroll") \
    for (int ks = 0; ks < 4; ++ks) \
        aF[mq][ks] = *(const bf16x8*)(lds + ABASE(bb) + (wr*2 + (mh))*8192 + mq*4096 \
                                      + lane31*128 + ((ks*32 + kb) ^ lx)); \
} while (0)
// B frags for 32-col block nh (4 k-steps = 4 x ds_read_b128)
#define PH_READ_B(bb, nh) do { \
    _Pragma("unroll") \
    for (int ks = 0; ks < 4; ++ks) \
        bF[nh][ks] = *(const bf16x8*)(lds + BBASE(bb) + wc*8192 + (nh)*4096 \
                                      + lane31*128 + ((ks*32 + kb) ^ lx)); \
} while (0)

// one quadrant: 2 m-quads x 4 k-steps = 8 MFMA 32x32x16
#define MFMA_Q(mh, nh) do { \
    _Pragma("unroll") \
    for (int mq = 0; mq < 2; ++mq) \
    _Pragma("unroll") \
    for (int ks = 0; ks < 4; ++ks) \
        acc[(mh)*2 + mq][nh] = __builtin_amdgcn_mfma_f32_32x32x16_bf16( \
            aF[mq][ks], bF[nh][ks], acc[(mh)*2 + mq][nh], 0, 0, 0); \
} while (0)

// MODE: 0 steady, 1 tail (stage B of t+1 only, drain), 2 last (compute only)
#define TILE(bb, kB, MODE) do { \
    PH_READ_A(bb, 0); PH_READ_B(bb, 0); \
    if ((MODE) <= 1) STAGE_B0((bb)^1, (kB) + 128); \
    BAR(); PRIO1; MFMA_Q(0, 0); PRIO0; BAR(); \
    PH_READ_B(bb, 1); \
    if ((MODE) <= 1) STAGE_B1((bb)^1, (kB) + 128); \
    BAR(); PRIO1; MFMA_Q(0, 1); PRIO0; BAR(); \
    PH_READ_A(bb, 1); \
    BAR(); PRIO1; MFMA_Q(1, 0); PRIO0; BAR(); \
    if ((MODE) == 0) STAGE_A(bb, (kB) + 256); \
    PRIO1; MFMA_Q(1, 1); PRIO0; \
    if ((MODE) == 0) WAITV(4); \
    if ((MODE) == 1) WAITV(0); \
    BAR(); \
} while (0)

__global__ __launch_bounds__(512, 2) void gemm_bt256(
    const unsigned short* __restrict__ Aq, const unsigned short* __restrict__ Bq,
    float* __restrict__ C)
{
    __shared__ char lds[131072];

    const int tid  = threadIdx.x;
    const int wave = tid >> 6;
    const int lane = tid & 63;
    const int wr   = wave >> 2;      // 0..1 (M)
    const int wc   = wave & 3;       // 0..3 (N)

    // XCD-aware bijective swizzle: 1376 wg = 8 * 172; tn-major (tm fastest)
    const int wg  = blockIdx.x;
    const int swz = (wg & 7) * 172 + (wg >> 3);
    const int tm  = swz & 31;        // M/256 = 32
    const int tn  = swz >> 5;        // N/256 = 43

    // ---- staging (pre-swizzled global source, linear LDS dest) ----
    const int gRow    = wave * 8 + (lane >> 3);
    const int gColSwz = (((lane & 7) ^ ((lane >> 3) & 7)) << 4);
    const char* aStageBase = (const char*)Aq + (size_t)(tm * 256 + gRow) * K2 + gColSwz;
    const char* bStageBase = (const char*)Bq + (size_t)(tn * 256 + gRow) * K2 + gColSwz;
    const int wOff = wave * 1024;

    // ---- ds_read addressing (swizzled) ----
    const int lane31 = lane & 31;
    const int lx = (lane & 7) << 4;          // XOR involution (row&7)<<4
    const int kb = (lane >> 5) << 4;         // k-byte base: 0 or 16

    f32x16 acc[4][2] = {};
    bf16x8 aF[2][4];
    bf16x8 bF[2][4];

    // ---- prologue: tile0 (A,B) + tile1 (A) ----
    STAGE_A(0, 0);
    STAGE_B0(0, 0); STAGE_B1(0, 0);
    STAGE_A(1, 128);
    WAITV(4);
    BAR();

    int kB = 0;
#pragma unroll 1
    for (int t = 0; t < 61; t += 2) {
        TILE(0, kB, 0);
        TILE(1, kB + 128, 0);
        kB += 256;
    }
    TILE(0, 62 * 128, 1);
    TILE(1, 63 * 128, 2);

    // ---- epilogue: C/D col = lane&31, row = (reg&3)+8*(reg>>2)+4*(lane>>5) ----
    const int row0 = tm * 256 + wr * 128 + 4 * (lane >> 5);
    const int col0 = tn * 256 + wc * 64 + lane31;
#pragma unroll
    for (int mi = 0; mi < 4; ++mi) {
#pragma unroll
        for (int ni = 0; ni < 2; ++ni) {
            const f32x16 v = acc[mi][ni];
            const size_t rb = (size_t)(row0 + mi * 32);
            const int    c  = col0 + ni * 32;
#pragma unroll
            for (int r = 0; r < 16; ++r)
                C[(rb + (r & 3) + 8 * (r >> 2)) * NDIM + c] = v[r];
        }
    }
}

extern "C" void kernel_launch(void* const* d_in, const int* in_sizes, int n_in,
                              void* d_out, int out_size, void* d_ws, size_t ws_size,
                              hipStream_t stream) {
    const float* x      = (const float*)d_in[0];
    const float* R      = (const float*)d_in[1];
    const float* scales = (const float*)d_in[2];
    const float* zeros  = (const float*)d_in[3];
    const int*   perm   = (const int*)d_in[4];
    const int*   qw     = (const int*)d_in[5];
    float*       out    = (float*)d_out;

    unsigned short* xt = (unsigned short*)d_ws;          // 64 MiB
    unsigned short* wd = xt + (size_t)M_TOK * KDIM;      // 86 MiB

    rotate_kernel<<<dim3(NBLK, M_TOK / 256), 256, 0, stream>>>(x, R, perm, xt);
    dequant_kernel<<<dim3((int)(((size_t)NDIM * KDIM) / 8 / 256)), 256, 0, stream>>>(qw, scales, zeros, wd);
    gemm_bt256<<<dim3((M_TOK / 256) * (NDIM / 256)), 512, 0, stream>>>(xt, wd, out);
}

// Round 6
// 872.784 us; speedup vs baseline: 1.0821x; 1.0821x over previous
//
#include <hip/hip_runtime.h>
#include <hip/hip_bf16.h>
#include <stdint.h>

#define M_TOK 8192
#define KDIM  4096
#define NDIM  11008
#define NBLK  256      // KDIM / 16
#define K2    8192     // KDIM * 2 bytes (row stride of xt/wd)

#define DQ_BLOCKS 11008   // (NDIM*KDIM)/16 elems per thread /256 threads
#define ROT_BLOCKS 8192   // 256 b * 32 m-chunks

typedef __bf16 bf16x8 __attribute__((ext_vector_type(8)));
typedef float  f32x4  __attribute__((ext_vector_type(4)));
typedef unsigned short ushort8 __attribute__((ext_vector_type(8)));

__device__ __forceinline__ unsigned short f2b(float f) {
    union { float f; unsigned int i; } v; v.f = f;
    unsigned int u = v.i;
    unsigned int r = (u + 0x7fffu + ((u >> 16) & 1u)) >> 16;
    return (unsigned short)r;
}

__device__ __forceinline__ void gl_lds16(const void* g, void* l) {
    __builtin_amdgcn_global_load_lds(
        (const __attribute__((address_space(1))) unsigned int*)g,
        (__attribute__((address_space(3))) unsigned int*)l, 16, 0, 0);
}

// ---------------------------------------------------------------------------
// Fused prep: blocks [0, DQ_BLOCKS) dequant (16 elem/thread),
//             blocks [DQ_BLOCKS, DQ_BLOCKS+ROT_BLOCKS) rotate.
// Overlaps the two independent memory streams in one launch.
// ---------------------------------------------------------------------------
__global__ __launch_bounds__(256) void prep_kernel(
    const float* __restrict__ x, const float* __restrict__ R,
    const int* __restrict__ perm, const int* __restrict__ qw,
    const float* __restrict__ scales, const float* __restrict__ zeros,
    unsigned short* __restrict__ xt, unsigned short* __restrict__ wd)
{
    const int bid = blockIdx.x;
    const int t   = threadIdx.x;

    if (bid < DQ_BLOCKS) {
        // ---- dequant: wd[n,k] = (q - zeros[n]) * scales[n] -> bf16 ----
        const size_t base = ((size_t)bid * 256 + t) * 16;
        const int n = (int)(base >> 12);        // /KDIM
        const float s = scales[n];
        const float z = zeros[n];
        const int4* qp = (const int4*)(qw + base);
        unsigned short o[16] __attribute__((aligned(16)));
#pragma unroll
        for (int c = 0; c < 4; ++c) {
            const int4 q4 = qp[c];
            o[c*4+0] = f2b(((float)q4.x - z) * s);
            o[c*4+1] = f2b(((float)q4.y - z) * s);
            o[c*4+2] = f2b(((float)q4.z - z) * s);
            o[c*4+3] = f2b(((float)q4.w - z) * s);
        }
        *(ushort8*)(wd + base)     = *(ushort8*)o;
        *(ushort8*)(wd + base + 8) = *(ushort8*)(o + 8);
    } else {
        // ---- rotate: xt[m, b*16+j] = sum_i x[m, perm[b*16+i]] * R[b,i,j] ----
        __shared__ float Rs[16][17];
        __shared__ int   ps[16];
        const int rb = bid - DQ_BLOCKS;
        const int b  = rb & 255;
        const int mc = rb >> 8;
        Rs[t >> 4][t & 15] = R[b * 256 + t];
        if (t < 16) ps[t] = perm[b * 16 + t];
        __syncthreads();

        const int m = mc * 256 + t;
        const float* xrow = x + (size_t)m * KDIM;
        float xv[16];
#pragma unroll
        for (int i = 0; i < 16; ++i) xv[i] = xrow[ps[i]];

        unsigned short o[16] __attribute__((aligned(16)));
#pragma unroll
        for (int j = 0; j < 16; ++j) {
            float acc = 0.f;
#pragma unroll
            for (int i = 0; i < 16; ++i) acc += xv[i] * Rs[i][j];
            o[j] = f2b(acc);
        }
        unsigned short* dst = xt + (size_t)m * KDIM + b * 16;
        *(ushort8*)dst       = *(ushort8*)o;
        *(ushort8*)(dst + 8) = *(ushort8*)(o + 8);
    }
}

// ---------------------------------------------------------------------------
// 256x256 8-phase GEMM (round-4 verified config): C[m,n] = sum_k A[m,k]*B[n,k]
// A: xt (M x K bf16), B: wd (N x K bf16), C: f32.
// 512 threads = 8 waves (2M x 4N); BK=64; LDS 128 KiB (2 buffers).
// mfma_f32_16x16x32_bf16 (16-row ds_read span -> 0 bank conflicts with the
// (row&7)<<4 XOR swizzle; 32x32 shape measured +4cyc/read conflicts, reverted).
// Staging pre-swizzles the GLOBAL source, LDS dest linear; counted vmcnt(4).
// ---------------------------------------------------------------------------
#define ABASE(bb) ((bb)*65536)
#define BBASE(bb) ((bb)*65536 + 32768)

#define BAR() do { asm volatile("" ::: "memory"); __builtin_amdgcn_s_barrier(); \
                   asm volatile("" ::: "memory"); } while (0)
#define WAITV(n) asm volatile("s_waitcnt vmcnt(" #n ")" ::: "memory")
#define PRIO1 __builtin_amdgcn_s_setprio(1)
#define PRIO0 __builtin_amdgcn_s_setprio(0)

#define STAGE_A(bb, kB) do { \
    gl_lds16(aStageBase + (size_t)(  0)*K2 + (kB), lds + ABASE(bb) +     0 + wOff); \
    gl_lds16(aStageBase + (size_t)( 64)*K2 + (kB), lds + ABASE(bb) +  8192 + wOff); \
    gl_lds16(aStageBase + (size_t)(128)*K2 + (kB), lds + ABASE(bb) + 16384 + wOff); \
    gl_lds16(aStageBase + (size_t)(192)*K2 + (kB), lds + ABASE(bb) + 24576 + wOff); \
} while (0)
#define STAGE_B0(bb, kB) do { \
    gl_lds16(bStageBase + (size_t)(  0)*K2 + (kB), lds + BBASE(bb) +     0 + wOff); \
    gl_lds16(bStageBase + (size_t)( 64)*K2 + (kB), lds + BBASE(bb) +  8192 + wOff); \
} while (0)
#define STAGE_B1(bb, kB) do { \
    gl_lds16(bStageBase + (size_t)(128)*K2 + (kB), lds + BBASE(bb) + 16384 + wOff); \
    gl_lds16(bStageBase + (size_t)(192)*K2 + (kB), lds + BBASE(bb) + 24576 + wOff); \
} while (0)

#define PH_READ_A(bb, mh) do { \
    _Pragma("unroll") \
    for (int mf = 0; mf < 4; ++mf) { \
        aF[mf][0] = *(const bf16x8*)(lds + ABASE(bb) + aRdBase + ((mh)*64 + mf*16)*128 + cs0); \
        aF[mf][1] = *(const bf16x8*)(lds + ABASE(bb) + aRdBase + ((mh)*64 + mf*16)*128 + cs1); \
    } \
} while (0)
#define PH_READ_B(bb, nh) do { \
    _Pragma("unroll") \
    for (int nf = 0; nf < 2; ++nf) { \
        bF[nh][nf][0] = *(const bf16x8*)(lds + BBASE(bb) + bRdBase + ((nh)*32 + nf*16)*128 + cs0); \
        bF[nh][nf][1] = *(const bf16x8*)(lds + BBASE(bb) + bRdBase + ((nh)*32 + nf*16)*128 + cs1); \
    } \
} while (0)

#define MFMA_Q(mh, nh) do { \
    _Pragma("unroll") \
    for (int mf = 0; mf < 4; ++mf) \
    _Pragma("unroll") \
    for (int nf = 0; nf < 2; ++nf) { \
        acc[(mh)*4+mf][(nh)*2+nf] = __builtin_amdgcn_mfma_f32_16x16x32_bf16( \
            aF[mf][0], bF[nh][nf][0], acc[(mh)*4+mf][(nh)*2+nf], 0, 0, 0); \
        acc[(mh)*4+mf][(nh)*2+nf] = __builtin_amdgcn_mfma_f32_16x16x32_bf16( \
            aF[mf][1], bF[nh][nf][1], acc[(mh)*4+mf][(nh)*2+nf], 0, 0, 0); \
    } \
} while (0)

// MODE: 0 steady, 1 tail (stage B of t+1 only, drain), 2 last (compute only)
#define TILE(bb, kB, MODE) do { \
    PH_READ_A(bb, 0); PH_READ_B(bb, 0); \
    if ((MODE) <= 1) STAGE_B0((bb)^1, (kB) + 128); \
    BAR(); PRIO1; MFMA_Q(0, 0); PRIO0; BAR(); \
    PH_READ_B(bb, 1); \
    if ((MODE) <= 1) STAGE_B1((bb)^1, (kB) + 128); \
    BAR(); PRIO1; MFMA_Q(0, 1); PRIO0; BAR(); \
    PH_READ_A(bb, 1); \
    BAR(); PRIO1; MFMA_Q(1, 0); PRIO0; BAR(); \
    if ((MODE) == 0) STAGE_A(bb, (kB) + 256); \
    PRIO1; MFMA_Q(1, 1); PRIO0; \
    if ((MODE) == 0) WAITV(4); \
    if ((MODE) == 1) WAITV(0); \
    BAR(); \
} while (0)

__global__ __launch_bounds__(512, 2) void gemm_bt256(
    const unsigned short* __restrict__ Aq, const unsigned short* __restrict__ Bq,
    float* __restrict__ C)
{
    __shared__ char lds[131072];

    const int tid  = threadIdx.x;
    const int wave = tid >> 6;
    const int lane = tid & 63;
    const int wr   = wave >> 2;      // 0..1 (M)
    const int wc   = wave & 3;       // 0..3 (N)

    // XCD-aware bijective swizzle: 1376 wg = 8 * 172; tn-major (tm fastest)
    const int wg  = blockIdx.x;
    const int swz = (wg & 7) * 172 + (wg >> 3);
    const int tm  = swz & 31;        // M/256 = 32
    const int tn  = swz >> 5;        // N/256 = 43

    // ---- staging (pre-swizzled global source, linear LDS dest) ----
    const int gRow    = wave * 8 + (lane >> 3);
    const int gColSwz = (((lane & 7) ^ ((lane >> 3) & 7)) << 4);
    const char* aStageBase = (const char*)Aq + (size_t)(tm * 256 + gRow) * K2 + gColSwz;
    const char* bStageBase = (const char*)Bq + (size_t)(tn * 256 + gRow) * K2 + gColSwz;
    const int wOff = wave * 1024;

    // ---- ds_read addressing (swizzled) ----
    const int laneRow128 = (lane & 15) * 128;
    const int lx  = (lane & 7) << 4;
    const int cs0 = (((lane >> 4) * 16)      ) ^ lx;   // k-cols 0..31
    const int cs1 = (((lane >> 4) * 16) + 64 ) ^ lx;   // k-cols 32..63
    const int aRdBase = wr * 16384 + laneRow128;
    const int bRdBase = (wc >> 1) * 16384 + (wc & 1) * 8192 + laneRow128;

    f32x4  acc[8][4] = {};
    bf16x8 aF[4][2];
    bf16x8 bF[2][2][2];

    // ---- prologue: tile0 (A,B) + tile1 (A) ----
    STAGE_A(0, 0);
    STAGE_B0(0, 0); STAGE_B1(0, 0);
    STAGE_A(1, 128);
    WAITV(4);
    BAR();

    int kB = 0;
#pragma unroll 1
    for (int t = 0; t < 61; t += 2) {
        TILE(0, kB, 0);
        TILE(1, kB + 128, 0);
        kB += 256;
    }
    TILE(0, 62 * 128, 1);
    TILE(1, 63 * 128, 2);

    // ---- epilogue: C/D layout col = lane&15, row = (lane>>4)*4 + reg ----
    const int row0 = tm * 256 + wr * 128 + (lane >> 4) * 4;
    const int col0 = tn * 256 + wc * 64 + (lane & 15);
#pragma unroll
    for (int mi = 0; mi < 8; ++mi) {
#pragma unroll
        for (int ni = 0; ni < 4; ++ni) {
            const f32x4 v = acc[mi][ni];
            const size_t r = (size_t)(row0 + mi * 16);
            const int    c = col0 + ni * 16;
            C[(r + 0) * NDIM + c] = v[0];
            C[(r + 1) * NDIM + c] = v[1];
            C[(r + 2) * NDIM + c] = v[2];
            C[(r + 3) * NDIM + c] = v[3];
        }
    }
}

extern "C" void kernel_launch(void* const* d_in, const int* in_sizes, int n_in,
                              void* d_out, int out_size, void* d_ws, size_t ws_size,
                              hipStream_t stream) {
    const float* x      = (const float*)d_in[0];
    const float* R      = (const float*)d_in[1];
    const float* scales = (const float*)d_in[2];
    const float* zeros  = (const float*)d_in[3];
    const int*   perm   = (const int*)d_in[4];
    const int*   qw     = (const int*)d_in[5];
    float*       out    = (float*)d_out;

    unsigned short* xt = (unsigned short*)d_ws;          // 64 MiB
    unsigned short* wd = xt + (size_t)M_TOK * KDIM;      // 86 MiB

    prep_kernel<<<dim3(DQ_BLOCKS + ROT_BLOCKS), 256, 0, stream>>>(
        x, R, perm, qw, scales, zeros, xt, wd);
    gemm_bt256<<<dim3((M_TOK / 256) * (NDIM / 256)), 512, 0, stream>>>(xt, wd, out);
}